// Round 8
// baseline (1023.934 us; speedup 1.0000x reference)
//
#include <hip/hip_runtime.h>
#include <math.h>

// Problem constants
#define Bsz 16
#define Kpt 4096
#define Cft 256
#define Pnp 1024
#define Smp 16
#define OUTCH 22
#define M0 (Bsz * Pnp * Smp)   // 262144
#define M1 (Bsz * Pnp)         // 16384
#define NSLOT 32               // stats contention-spreading slots

// Workspace layout (float units; bf16 buffers use half-slots)
#define OFF_FT      ((size_t)0)            // ft bf16 (B,K,C)
#define OFF_YA      ((size_t)8388608)      // y0/y1 bf16 (M0 x 128)
#define OFF_M2      ((size_t)25165824)     // m2 f32 (M1 x 128)
#define OFF_YF1     ((size_t)27262976)     // yF1 bf16 (M1 x 128)
#define OFF_YF2     ((size_t)28311552)     // yF2 f32 (M1 x 128)
#define OFF_W0T     ((size_t)30408704)     // swizzled bf16 weights
#define OFF_W1T     ((size_t)30425088)
#define OFF_W2T     ((size_t)30433280)
#define OFF_WF1T    ((size_t)30441472)
#define OFF_WF2T    ((size_t)30449664)
#define OFF_STATS   ((size_t)30457856)     // 5 stats x NSLOT x 256 f32
#define OFF_GIDX    ((size_t)30498816)     // 262144 int
#define OFF_NEWXYZ  ((size_t)30760960)

#define ST_STRIDE (NSLOT * 256)

typedef __attribute__((ext_vector_type(8))) short bf16x8;
typedef __attribute__((ext_vector_type(4))) float f32x4;

__device__ __forceinline__ unsigned short f2bf(float x) {
    union { float f; unsigned u; } v; v.f = x;
    unsigned r = v.u + 0x7fffu + ((v.u >> 16) & 1u);  // RNE
    return (unsigned short)(r >> 16);
}
__device__ __forceinline__ float bf2f(unsigned short u) {
    union { unsigned u; float f; } v; v.u = ((unsigned)u) << 16; return v.f;
}

// sum NSLOT slots for channel tid (tid<128): sm=sum, sq=sumsq
__device__ __forceinline__ void read_stats(const float* st, int tid, float& sm, float& sq) {
    sm = 0.f; sq = 0.f;
#pragma unroll
    for (int s = 0; s < NSLOT; ++s) {
        sm += st[s * 256 + tid];
        sq += st[s * 256 + 128 + tid];
    }
}

// ---------------------------------------------------------------- FPS (16 blocks) + fused transpose_feat (1024 blocks)
// + fused weight swizzle (16 blocks). K-loop touches LDS/registers only (no global store -> no per-iter vmcnt drain
// at the barrier); selected centers flushed from sel_s once at the end.
template <int CTRL>
__device__ __forceinline__ unsigned long long dpp_max_step(unsigned long long key) {
    int lo = (int)(unsigned)key, hi = (int)(key >> 32);
    int slo = __builtin_amdgcn_update_dpp(0, lo, CTRL, 0xf, 0xf, true);
    int shi = __builtin_amdgcn_update_dpp(0, hi, CTRL, 0xf, 0xf, true);
    unsigned long long other = ((unsigned long long)(unsigned)shi << 32) | (unsigned)slo;
    return other > key ? other : key;
}

__global__ __launch_bounds__(256) void fps_fused(const float* __restrict__ xyz, float* __restrict__ new_xyz,
                                                 const float* __restrict__ features, unsigned short* __restrict__ ft,
                                                 const float* __restrict__ w0, const float* __restrict__ w1m,
                                                 const float* __restrict__ w2m, const float* __restrict__ wf1,
                                                 const float* __restrict__ wf2,
                                                 unsigned short* __restrict__ W0T, unsigned short* __restrict__ W1T,
                                                 unsigned short* __restrict__ W2T, unsigned short* __restrict__ WF1T,
                                                 unsigned short* __restrict__ WF2T) {
    __shared__ float4 xyz_s[Kpt];                 // 64 KB (transpose blocks reuse as tile)
    __shared__ float4 sel_s[Pnp];                 // 16 KB: selected centers, flushed once after the loop
    __shared__ unsigned long long red[2][4];
    int bid = blockIdx.x, tid = threadIdx.x;

    if (bid < 16) {
        int b = bid, wid = tid >> 6, lane = tid & 63;
        for (int k = tid; k < Kpt; k += 256) {
            float x = xyz[(size_t)b * Kpt * 3 + k * 3 + 0];
            float y = xyz[(size_t)b * Kpt * 3 + k * 3 + 1];
            float z = xyz[(size_t)b * Kpt * 3 + k * 3 + 2];
            xyz_s[k] = make_float4(x, y, z, 0.f);
        }
        __syncthreads();
        float px[16], py[16], pz[16], mind[16];
#pragma unroll
        for (int j = 0; j < 16; ++j) {
            float4 p = xyz_s[tid + j * 256];
            px[j] = p.x; py[j] = p.y; pz[j] = p.z;
            mind[j] = 1e10f;
        }
        float lx = xyz_s[0].x, ly = xyz_s[0].y, lz = xyz_s[0].z;
        if (tid == 0) sel_s[0] = make_float4(lx, ly, lz, 0.f);
        for (int it = 1; it < Pnp; ++it) {
            float bestv = -1.0f;
            int bestk = 0;
#pragma unroll
            for (int j = 0; j < 16; ++j) {
                float dx = __fsub_rn(px[j], lx);
                float dy = __fsub_rn(py[j], ly);
                float dz = __fsub_rn(pz[j], lz);
                float d = __fadd_rn(__fadd_rn(__fmul_rn(dx, dx), __fmul_rn(dy, dy)), __fmul_rn(dz, dz));
                float m = fminf(mind[j], d);
                mind[j] = m;
                if (m > bestv) { bestv = m; bestk = tid + j * 256; }
            }
            unsigned long long key = ((unsigned long long)__float_as_uint(bestv) << 32) | (unsigned)(~bestk);
            key = dpp_max_step<0x111>(key);
            key = dpp_max_step<0x112>(key);
            key = dpp_max_step<0x114>(key);
            key = dpp_max_step<0x118>(key);
            key = dpp_max_step<0x142>(key);
            key = dpp_max_step<0x143>(key);
            if (lane == 63) red[it & 1][wid] = key;
            __syncthreads();
            unsigned long long gkey = red[it & 1][0];
#pragma unroll
            for (int w = 1; w < 4; ++w) {
                unsigned long long ok = red[it & 1][w];
                if (ok > gkey) gkey = ok;
            }
            int win = (int)(~(unsigned)gkey);
            float4 c = xyz_s[win];
            lx = c.x; ly = c.y; lz = c.z;
            if (tid == 0) sel_s[it] = c;
        }
        __syncthreads();
        // coalesced flush of the 1024 selected centers
        for (int e = tid; e < Pnp * 3; e += 256) {
            int p = e / 3, cc = e - p * 3;
            const float* f = (const float*)&sel_s[p];
            new_xyz[(size_t)b * Pnp * 3 + e] = f[cc];
        }
    } else if (bid < 16 + 1024) {
        float* tile = (float*)xyz_s;              // 32x33 f32
        int tx = tid & 31, ty = tid >> 5;         // 32 x 8
        int t0 = (bid - 16) * 16;
        for (int tt = 0; tt < 16; ++tt) {
            int t = t0 + tt;
            int k0 = (t & 127) << 5;
            int c0 = ((t >> 7) & 7) << 5;
            int b2 = t >> 10;
            __syncthreads();
#pragma unroll
            for (int j = 0; j < 4; ++j)
                tile[(ty + j * 8) * 33 + tx] = features[((size_t)b2 * Cft + c0 + ty + j * 8) * Kpt + k0 + tx];
            __syncthreads();
#pragma unroll
            for (int j = 0; j < 4; ++j)
                ft[((size_t)b2 * Kpt + k0 + ty + j * 8) * Cft + c0 + tx] = f2bf(tile[tx * 33 + ty + j * 8]);
        }
    } else {
        int base = (bid - (16 + 1024)) * 6144;
#pragma unroll 1
        for (int i = 0; i < 24; ++i) {
            int e = base + i * 256 + tid;
            const float* src; unsigned short* dst; int eo, stride, off;
            if (e < 32768) { src = w0; dst = W0T; eo = e; stride = 259; off = 3; }
            else {
                int r = e - 32768; int which = r >> 14; eo = r & 16383; stride = 128; off = 0;
                src = (which == 0) ? w1m : (which == 1) ? w2m : (which == 2) ? wf1 : wf2;
                dst = (which == 0) ? W1T : (which == 1) ? W2T : (which == 2) ? WF1T : WF2T;
            }
            int j = eo & 7, np = (eo >> 3) & 15, q = (eo >> 7) & 3, S = (eo >> 9) & 7, c = eo >> 12;
            dst[eo] = f2bf(src[(size_t)(S * 16 + np) * stride + off + c * 32 + q * 8 + j]);
        }
    }
}

// ---------------------------------------------------------------- ball query
__global__ __launch_bounds__(256) void ballq_kernel(const float* __restrict__ xyz, const float* __restrict__ new_xyz,
                                                    int* __restrict__ gidx) {
    __shared__ float xyz_s[Kpt * 3];
    __shared__ int idxbuf[64][16];
    __shared__ int have_s[64];
    int bx = blockIdx.x;
    int b = bx >> 4, chunk = bx & 15;
    int tid = threadIdx.x, w = tid >> 6, lane = tid & 63;
    for (int e = tid; e < Kpt * 3; e += 256) xyz_s[e] = xyz[(size_t)b * Kpt * 3 + e];
    __syncthreads();
    const float R2 = (float)(0.3 * 0.3);
    unsigned long long lmask = (lane == 63) ? 0x7fffffffffffffffull : ((1ull << lane) - 1ull);
    for (int t = 0; t < 16; ++t) {
        int ql = w * 16 + t;
        size_t bp = (size_t)b * Pnp + chunk * 64 + ql;
        float nx = new_xyz[bp * 3 + 0], ny = new_xyz[bp * 3 + 1], nz = new_xyz[bp * 3 + 2];
        int have = 0;
        for (int r = 0; r < 64; ++r) {
            int k = r * 64 + lane;
            float dx = __fsub_rn(nx, xyz_s[k * 3 + 0]);
            float dy = __fsub_rn(ny, xyz_s[k * 3 + 1]);
            float dz = __fsub_rn(nz, xyz_s[k * 3 + 2]);
            float d2 = __fadd_rn(__fadd_rn(__fmul_rn(dx, dx), __fmul_rn(dy, dy)), __fmul_rn(dz, dz));
            bool inb = d2 < R2;
            unsigned long long mask = __ballot(inb);
            if (mask) {
                int rank = __popcll(mask & lmask);
                if (inb && (have + rank) < 16) idxbuf[ql][have + rank] = k;
                have += __popcll(mask);
                if (have >= 16) break;
            }
        }
        if (lane == 0) have_s[ql] = (have > 16) ? 16 : have;
    }
    __syncthreads();
    for (int e = tid; e < 1024; e += 256) {
        int ql = e >> 4, slot = e & 15;
        int h = have_s[ql];
        int v = (h == 0) ? (Kpt - 1) : ((slot < h) ? idxbuf[ql][slot] : idxbuf[ql][0]);
        size_t bp = (size_t)b * Pnp + chunk * 64 + ql;
        gidx[bp * 16 + slot] = v;
    }
}

// ---------------------------------------------------------------- GEMM0: gather + K=256 bf16 MFMA + f32 xyz epilogue,
// out bf16, slotted fused stats.
__global__ __launch_bounds__(256) void gemm0_mfma(const unsigned short* __restrict__ ft, const unsigned short* __restrict__ Bsw,
                                                  const float* __restrict__ xyz, const float* __restrict__ new_xyz,
                                                  const int* __restrict__ gidx, const float* __restrict__ w0,
                                                  unsigned short* __restrict__ yout, float* __restrict__ statsOut) {
    __shared__ unsigned short Asw[128 * 256];   // 64 KB
    __shared__ unsigned short Bs[256 * 128];    // 64 KB
    __shared__ float4 gxyz_s[128];
    __shared__ float4 w03s[128];
    __shared__ int krow_s[128];
    __shared__ float ssum[128], ssq[128];
    int tid = threadIdx.x;
    int wave = tid >> 6, lane = tid & 63, q = lane >> 4, l = lane & 15;
    int wm = wave >> 1, wn = wave & 1;
    size_t r0 = (size_t)blockIdx.x * 128;
    int b = (int)(r0 >> 14);

    if (tid < 128) {
        ssum[tid] = 0.f; ssq[tid] = 0.f;
        size_t r = r0 + tid;
        int kg = gidx[r];
        krow_s[tid] = kg;
        size_t bp = r >> 4;
        float gx = (xyz[((size_t)b * Kpt + kg) * 3 + 0] - new_xyz[bp * 3 + 0]) / 0.3f;
        float gy = (xyz[((size_t)b * Kpt + kg) * 3 + 1] - new_xyz[bp * 3 + 1]) / 0.3f;
        float gz = (xyz[((size_t)b * Kpt + kg) * 3 + 2] - new_xyz[bp * 3 + 2]) / 0.3f;
        gxyz_s[tid] = make_float4(gx, gy, gz, 0.f);
    } else {
        int o = tid - 128;
        w03s[o] = make_float4(w0[(size_t)o * 259 + 0], w0[(size_t)o * 259 + 1], w0[(size_t)o * 259 + 2], 0.f);
    }
#pragma unroll
    for (int i = 0; i < 16; ++i) {
        int e = i * 256 + tid;
        *(int4*)&Bs[e * 8] = *(const int4*)&Bsw[e * 8];
    }
    __syncthreads();
#pragma unroll
    for (int i = 0; i < 16; ++i) {
        int idx = i * 4 + wave;
        int G = idx >> 3, c = idx & 7;
        int kg = krow_s[G * 16 + l];
        const unsigned short* src = ft + ((size_t)b * Kpt + kg) * 256 + c * 32 + q * 8;
        *(int4*)&Asw[(size_t)((c * 8 + G) * 64 + lane) * 8] = *(const int4*)src;
    }
    __syncthreads();

    f32x4 acc[4][4];
    f32x4 zz = {0.f, 0.f, 0.f, 0.f};
#pragma unroll
    for (int mi = 0; mi < 4; ++mi)
#pragma unroll
        for (int ni = 0; ni < 4; ++ni) acc[mi][ni] = zz;

    for (int c = 0; c < 8; ++c) {
        bf16x8 af[4], bfr[4];
#pragma unroll
        for (int mi = 0; mi < 4; ++mi)
            af[mi] = *(const bf16x8*)&Asw[(size_t)((c * 8 + wm * 4 + mi) * 64 + lane) * 8];
#pragma unroll
        for (int ni = 0; ni < 4; ++ni)
            bfr[ni] = *(const bf16x8*)&Bs[(size_t)((c * 8 + wn * 4 + ni) * 64 + lane) * 8];
#pragma unroll
        for (int mi = 0; mi < 4; ++mi)
#pragma unroll
            for (int ni = 0; ni < 4; ++ni)
                acc[mi][ni] = __builtin_amdgcn_mfma_f32_16x16x32_bf16(af[mi], bfr[ni], acc[mi][ni], 0, 0, 0);
    }
    float4 wv[4];
#pragma unroll
    for (int ni = 0; ni < 4; ++ni) wv[ni] = w03s[wn * 64 + ni * 16 + l];
    float psum[4] = {0.f, 0.f, 0.f, 0.f}, psq[4] = {0.f, 0.f, 0.f, 0.f};
#pragma unroll
    for (int mi = 0; mi < 4; ++mi) {
#pragma unroll
        for (int r = 0; r < 4; ++r) {
            int mloc = wm * 64 + mi * 16 + q * 4 + r;
            float4 g = gxyz_s[mloc];
            size_t rowg = r0 + mloc;
#pragma unroll
            for (int ni = 0; ni < 4; ++ni) {
                int colg = wn * 64 + ni * 16 + l;
                float val = acc[mi][ni][r] + g.x * wv[ni].x + g.y * wv[ni].y + g.z * wv[ni].z;
                psum[ni] += val; psq[ni] += val * val;
                yout[rowg * 128 + colg] = f2bf(val);
            }
        }
    }
#pragma unroll
    for (int ni = 0; ni < 4; ++ni) {
        float s = psum[ni], sq = psq[ni];
        s += __shfl_xor(s, 16); sq += __shfl_xor(sq, 16);
        s += __shfl_xor(s, 32); sq += __shfl_xor(sq, 32);
        if (q == 0) {
            int colg = wn * 64 + ni * 16 + l;
            atomicAdd(&ssum[colg], s);
            atomicAdd(&ssq[colg], sq);
        }
    }
    __syncthreads();
    if (tid < 128) {
        float* stSlot = statsOut + (blockIdx.x & (NSLOT - 1)) * 256;
        atomicAdd(&stSlot[tid], ssum[tid]);
        atomicAdd(&stSlot[128 + tid], ssq[tid]);
    }
}

// ---------------------------------------------------------------- generic K=128 bf16 MFMA GEMM: A bf16 or f32 (+opt BN-ReLU),
// opt bias, out bf16 or f32, slotted fused stats. In-place safe.
__global__ __launch_bounds__(256) void gemm_mfma_bn(const unsigned short* __restrict__ A, const float* __restrict__ Af32,
                                                    const unsigned short* __restrict__ Bsw,
                                                    unsigned short* __restrict__ OutBf, float* __restrict__ OutF,
                                                    const float* __restrict__ statsIn, const float* __restrict__ gamma,
                                                    const float* __restrict__ beta, const float* __restrict__ bias,
                                                    float invN, float* __restrict__ statsOut) {
    __shared__ unsigned short Asw[128 * 128];
    __shared__ unsigned short Bs[128 * 128];
    __shared__ float scs[128], shs[128], ssum[128], ssq[128];
    int tid = threadIdx.x;
    int wave = tid >> 6, lane = tid & 63, q = lane >> 4, l = lane & 15;
    int wm = wave >> 1, wn = wave & 1;
    size_t r0 = (size_t)blockIdx.x * 128;
    bool hasT = (statsIn != nullptr);
    if (tid < 128) {
        ssum[tid] = 0.f; ssq[tid] = 0.f;
        if (hasT) {
            float sm, sq;
            read_stats(statsIn, tid, sm, sq);
            float m = sm * invN;
            float v = sq * invN - m * m;
            float sc = gamma[tid] / sqrtf(v + 1e-5f);
            scs[tid] = sc;
            shs[tid] = beta[tid] - m * sc;
        }
    }
#pragma unroll
    for (int i = 0; i < 8; ++i) {
        int e = i * 256 + tid;
        *(int4*)&Bs[e * 8] = *(const int4*)&Bsw[e * 8];
    }
    __syncthreads();
#pragma unroll
    for (int i = 0; i < 8; ++i) {
        int idx = i * 4 + wave;
        int G = idx >> 2, c = idx & 3;
        int cb = c * 32 + q * 8;
        int4 v;
        if (Af32) {
            const float* srcf = Af32 + (r0 + G * 16 + l) * 128 + cb;
            float4 v0 = *(const float4*)srcf;
            float4 v1 = *(const float4*)(srcf + 4);
            float vv[8] = {v0.x, v0.y, v0.z, v0.w, v1.x, v1.y, v1.z, v1.w};
            unsigned short* u = (unsigned short*)&v;
#pragma unroll
            for (int t = 0; t < 8; ++t) {
                float f = vv[t];
                if (hasT) f = fmaxf(0.f, f * scs[cb + t] + shs[cb + t]);
                u[t] = f2bf(f);
            }
        } else {
            const unsigned short* src = A + (r0 + G * 16 + l) * 128 + cb;
            v = *(const int4*)src;
            if (hasT) {
                unsigned short* u = (unsigned short*)&v;
#pragma unroll
                for (int t = 0; t < 8; ++t) {
                    float f = bf2f(u[t]);
                    u[t] = f2bf(fmaxf(0.f, f * scs[cb + t] + shs[cb + t]));
                }
            }
        }
        *(int4*)&Asw[(size_t)((c * 8 + G) * 64 + lane) * 8] = v;
    }
    __syncthreads();

    f32x4 acc[4][4];
    f32x4 zz = {0.f, 0.f, 0.f, 0.f};
#pragma unroll
    for (int mi = 0; mi < 4; ++mi)
#pragma unroll
        for (int ni = 0; ni < 4; ++ni) acc[mi][ni] = zz;

#pragma unroll
    for (int c = 0; c < 4; ++c) {
        bf16x8 af[4], bfr[4];
#pragma unroll
        for (int mi = 0; mi < 4; ++mi)
            af[mi] = *(const bf16x8*)&Asw[(size_t)((c * 8 + wm * 4 + mi) * 64 + lane) * 8];
#pragma unroll
        for (int ni = 0; ni < 4; ++ni)
            bfr[ni] = *(const bf16x8*)&Bs[(size_t)((c * 8 + wn * 4 + ni) * 64 + lane) * 8];
#pragma unroll
        for (int mi = 0; mi < 4; ++mi)
#pragma unroll
            for (int ni = 0; ni < 4; ++ni)
                acc[mi][ni] = __builtin_amdgcn_mfma_f32_16x16x32_bf16(af[mi], bfr[ni], acc[mi][ni], 0, 0, 0);
    }
    float psum[4] = {0.f, 0.f, 0.f, 0.f}, psq[4] = {0.f, 0.f, 0.f, 0.f};
#pragma unroll
    for (int mi = 0; mi < 4; ++mi) {
#pragma unroll
        for (int r = 0; r < 4; ++r) {
            size_t rowg = r0 + wm * 64 + mi * 16 + q * 4 + r;
#pragma unroll
            for (int ni = 0; ni < 4; ++ni) {
                int colg = wn * 64 + ni * 16 + l;
                float val = acc[mi][ni][r] + (bias ? bias[colg] : 0.f);
                psum[ni] += val; psq[ni] += val * val;
                if (OutBf) OutBf[rowg * 128 + colg] = f2bf(val);
                else OutF[rowg * 128 + colg] = val;
            }
        }
    }
#pragma unroll
    for (int ni = 0; ni < 4; ++ni) {
        float s = psum[ni], sq = psq[ni];
        s += __shfl_xor(s, 16); sq += __shfl_xor(sq, 16);
        s += __shfl_xor(s, 32); sq += __shfl_xor(sq, 32);
        if (q == 0) {
            int colg = wn * 64 + ni * 16 + l;
            atomicAdd(&ssum[colg], s);
            atomicAdd(&ssq[colg], sq);
        }
    }
    __syncthreads();
    if (tid < 128) {
        float* stSlot = statsOut + (blockIdx.x & (NSLOT - 1)) * 256;
        atomicAdd(&stSlot[tid], ssum[tid]);
        atomicAdd(&stSlot[128 + tid], ssq[tid]);
    }
}

// ---------------------------------------------------------------- GEMM2: A bf16 + BN1-ReLU, no y2 write; slotted stats2 +
// per-16-row-group max (BN2 monotone: max commutes with relu∘bn).
__global__ __launch_bounds__(256) void gemm2_max(const unsigned short* __restrict__ A, const unsigned short* __restrict__ Bsw,
                                                 const float* __restrict__ statsIn, const float* __restrict__ gamma,
                                                 const float* __restrict__ beta, float invN,
                                                 float* __restrict__ m2, float* __restrict__ statsOut) {
    __shared__ unsigned short Asw[128 * 128];
    __shared__ unsigned short Bs[128 * 128];
    __shared__ float scs[128], shs[128], ssum[128], ssq[128];
    __shared__ float smax[8][128];
    int tid = threadIdx.x;
    int wave = tid >> 6, lane = tid & 63, q = lane >> 4, l = lane & 15;
    int wm = wave >> 1, wn = wave & 1;
    size_t r0 = (size_t)blockIdx.x * 128;
    if (tid < 128) {
        ssum[tid] = 0.f; ssq[tid] = 0.f;
        float sm, sq;
        read_stats(statsIn, tid, sm, sq);
        float m = sm * invN;
        float v = sq * invN - m * m;
        float sc = gamma[tid] / sqrtf(v + 1e-5f);
        scs[tid] = sc;
        shs[tid] = beta[tid] - m * sc;
    }
#pragma unroll
    for (int i = 0; i < 8; ++i) {
        int e = i * 256 + tid;
        *(int4*)&Bs[e * 8] = *(const int4*)&Bsw[e * 8];
    }
    __syncthreads();
#pragma unroll
    for (int i = 0; i < 8; ++i) {
        int idx = i * 4 + wave;
        int G = idx >> 2, c = idx & 3;
        const unsigned short* src = A + (r0 + G * 16 + l) * 128 + c * 32 + q * 8;
        int4 v = *(const int4*)src;
        unsigned short* u = (unsigned short*)&v;
        int cb = c * 32 + q * 8;
#pragma unroll
        for (int t = 0; t < 8; ++t) {
            float f = bf2f(u[t]);
            u[t] = f2bf(fmaxf(0.f, f * scs[cb + t] + shs[cb + t]));
        }
        *(int4*)&Asw[(size_t)((c * 8 + G) * 64 + lane) * 8] = v;
    }
    __syncthreads();

    f32x4 acc[4][4];
    f32x4 zz = {0.f, 0.f, 0.f, 0.f};
#pragma unroll
    for (int mi = 0; mi < 4; ++mi)
#pragma unroll
        for (int ni = 0; ni < 4; ++ni) acc[mi][ni] = zz;

#pragma unroll
    for (int c = 0; c < 4; ++c) {
        bf16x8 af[4], bfr[4];
#pragma unroll
        for (int mi = 0; mi < 4; ++mi)
            af[mi] = *(const bf16x8*)&Asw[(size_t)((c * 8 + wm * 4 + mi) * 64 + lane) * 8];
#pragma unroll
        for (int ni = 0; ni < 4; ++ni)
            bfr[ni] = *(const bf16x8*)&Bs[(size_t)((c * 8 + wn * 4 + ni) * 64 + lane) * 8];
#pragma unroll
        for (int mi = 0; mi < 4; ++mi)
#pragma unroll
            for (int ni = 0; ni < 4; ++ni)
                acc[mi][ni] = __builtin_amdgcn_mfma_f32_16x16x32_bf16(af[mi], bfr[ni], acc[mi][ni], 0, 0, 0);
    }
    float psum[4] = {0.f, 0.f, 0.f, 0.f}, psq[4] = {0.f, 0.f, 0.f, 0.f};
#pragma unroll
    for (int mi = 0; mi < 4; ++mi) {
#pragma unroll
        for (int ni = 0; ni < 4; ++ni) {
            float gm = -1e30f;
#pragma unroll
            for (int r = 0; r < 4; ++r) {
                float val = acc[mi][ni][r];
                psum[ni] += val; psq[ni] += val * val;
                gm = fmaxf(gm, val);
            }
            gm = fmaxf(gm, __shfl_xor(gm, 16));
            gm = fmaxf(gm, __shfl_xor(gm, 32));
            if (q == 0) smax[wm * 4 + mi][wn * 64 + ni * 16 + l] = gm;
        }
    }
#pragma unroll
    for (int ni = 0; ni < 4; ++ni) {
        float s = psum[ni], sq = psq[ni];
        s += __shfl_xor(s, 16); sq += __shfl_xor(sq, 16);
        s += __shfl_xor(s, 32); sq += __shfl_xor(sq, 32);
        if (q == 0) {
            int colg = wn * 64 + ni * 16 + l;
            atomicAdd(&ssum[colg], s);
            atomicAdd(&ssq[colg], sq);
        }
    }
    __syncthreads();
#pragma unroll
    for (int i = 0; i < 4; ++i) {
        int e = i * 256 + tid;
        int g = e >> 7, cc = e & 127;
        m2[((size_t)blockIdx.x * 8 + g) * 128 + cc] = smax[g][cc];
    }
    if (tid < 128) {
        float* stSlot = statsOut + (blockIdx.x & (NSLOT - 1)) * 256;
        atomicAdd(&stSlot[tid], ssum[tid]);
        atomicAdd(&stSlot[128 + tid], ssq[tid]);
    }
}

// ---------------------------------------------------------------- final: n2=BN-ReLU(yf), net=n2@w3^T+b3, out assembly
__global__ __launch_bounds__(256) void final_k(const float* __restrict__ yf, const float* __restrict__ st,
                                               const float* __restrict__ gamma, const float* __restrict__ beta,
                                               const float* __restrict__ w3, const float* __restrict__ b3,
                                               const float* __restrict__ new_xyz, float* __restrict__ out) {
    __shared__ float n2s[8][128];
    __shared__ float w3s[22 * 132];
    __shared__ float scf[128], shf[128];
    int tid = threadIdx.x;
    size_t r0 = (size_t)blockIdx.x * 8;
    if (tid < 128) {
        const float invN = 1.f / (float)M1;
        float sm, sq;
        read_stats(st, tid, sm, sq);
        float m = sm * invN;
        float v = sq * invN - m * m;
        float sc = gamma[tid] / sqrtf(v + 1e-5f);
        scf[tid] = sc;
        shf[tid] = beta[tid] - m * sc;
    }
    __syncthreads();
#pragma unroll
    for (int i = 0; i < 4; ++i) {
        int e = tid + i * 256;
        int rl = e >> 7, c = e & 127;
        float raw = yf[(r0 + rl) * 128 + c];
        n2s[rl][c] = fmaxf(0.f, raw * scf[c] + shf[c]);
    }
#pragma unroll
    for (int i = 0; i < 11; ++i) {
        int e = tid + i * 256;
        int o = e >> 7, c = e & 127;
        w3s[o * 132 + c] = w3[e];
    }
    __syncthreads();
    int rl = tid >> 5, o = tid & 31;
    if (o < OUTCH) {
        float dot = 0.f;
#pragma unroll 4
        for (int c = 0; c < 128; ++c) dot += n2s[rl][c] * w3s[o * 132 + c];
        float v = dot + b3[o];
        if (o < 3) v += new_xyz[(r0 + rl) * 3 + o];
        out[(r0 + rl) * OUTCH + o] = v;
    }
}

extern "C" void kernel_launch(void* const* d_in, const int* in_sizes, int n_in,
                              void* d_out, int out_size, void* d_ws, size_t ws_size,
                              hipStream_t stream) {
    (void)in_sizes; (void)n_in; (void)out_size; (void)ws_size;
    const float* xyz = (const float*)d_in[0];
    const float* features = (const float*)d_in[1];
    const float* w0 = (const float*)d_in[2];
    const float* g0 = (const float*)d_in[3];
    const float* be0 = (const float*)d_in[4];
    const float* w1m = (const float*)d_in[5];
    const float* g1m = (const float*)d_in[6];
    const float* be1m = (const float*)d_in[7];
    const float* w2m = (const float*)d_in[8];
    const float* g2m = (const float*)d_in[9];
    const float* be2m = (const float*)d_in[10];
    const float* wf1 = (const float*)d_in[11];
    const float* bf1 = (const float*)d_in[12];
    const float* gf1 = (const float*)d_in[13];
    const float* bef1 = (const float*)d_in[14];
    const float* wf2 = (const float*)d_in[15];
    const float* bf2 = (const float*)d_in[16];
    const float* gf2 = (const float*)d_in[17];
    const float* bef2 = (const float*)d_in[18];
    const float* w3 = (const float*)d_in[19];
    const float* b3 = (const float*)d_in[20];
    float* ws = (float*)d_ws;
    unsigned short* ft = (unsigned short*)(ws + OFF_FT);
    unsigned short* yA = (unsigned short*)(ws + OFF_YA);
    float* m2 = ws + OFF_M2;
    unsigned short* yF1 = (unsigned short*)(ws + OFF_YF1);
    float* yF2 = ws + OFF_YF2;
    unsigned short* W0T = (unsigned short*)(ws + OFF_W0T);
    unsigned short* W1T = (unsigned short*)(ws + OFF_W1T);
    unsigned short* W2T = (unsigned short*)(ws + OFF_W2T);
    unsigned short* WF1T = (unsigned short*)(ws + OFF_WF1T);
    unsigned short* WF2T = (unsigned short*)(ws + OFF_WF2T);
    float* st = ws + OFF_STATS;          // 5 x NSLOT x 256
    int* gidx = (int*)(ws + OFF_GIDX);
    float* nxyz = ws + OFF_NEWXYZ;

    hipMemsetAsync((void*)st, 0, 5 * ST_STRIDE * sizeof(float), stream);

    fps_fused<<<16 + 1024 + 16, 256, 0, stream>>>(xyz, nxyz, features, ft,
                                                  w0, w1m, w2m, wf1, wf2,
                                                  W0T, W1T, W2T, WF1T, WF2T);
    ballq_kernel<<<256, 256, 0, stream>>>(xyz, nxyz, gidx);

    // st0 = stats(y0), st1 = stats(y1), st2 = stats(y2), st3 = stats(yF1), st4 = stats(yF2)
    gemm0_mfma<<<M0 / 128, 256, 0, stream>>>(ft, W0T, xyz, nxyz, gidx, w0, yA, st);
    gemm_mfma_bn<<<M0 / 128, 256, 0, stream>>>(yA, nullptr, W1T, yA, nullptr,
                                               st, g0, be0, nullptr, 1.f / (float)M0, st + ST_STRIDE);
    gemm2_max<<<M0 / 128, 256, 0, stream>>>(yA, W2T, st + ST_STRIDE, g1m, be1m, 1.f / (float)M0,
                                            m2, st + 2 * ST_STRIDE);
    // gemmF1: A = BN2-ReLU(m2) [f32 path], out yF1 bf16 + bias bf1, stats -> st3
    gemm_mfma_bn<<<M1 / 128, 256, 0, stream>>>(nullptr, m2, WF1T, yF1, nullptr,
                                               st + 2 * ST_STRIDE, g2m, be2m, bf1, 1.f / (float)M0, st + 3 * ST_STRIDE);
    // gemmF2: A = BN3-ReLU(yF1) [bf16], out yF2 f32 + bias bf2, stats -> st4
    gemm_mfma_bn<<<M1 / 128, 256, 0, stream>>>(yF1, nullptr, WF2T, nullptr, yF2,
                                               st + 3 * ST_STRIDE, gf1, bef1, bf2, 1.f / (float)M1, st + 4 * ST_STRIDE);
    final_k<<<M1 / 8, 256, 0, stream>>>(yF2, st + 4 * ST_STRIDE, gf2, bef2, w3, b3, nxyz, (float*)d_out);
}

// Round 9
// 955.390 us; speedup vs baseline: 1.0717x; 1.0717x over previous
//
#include <hip/hip_runtime.h>
#include <math.h>

// Problem constants
#define Bsz 16
#define Kpt 4096
#define Cft 256
#define Pnp 1024
#define Smp 16
#define OUTCH 22
#define M0 (Bsz * Pnp * Smp)   // 262144
#define M1 (Bsz * Pnp)         // 16384
#define NSLOT 32               // stats contention-spreading slots

// Workspace layout (float units; bf16 buffers use half-slots)
#define OFF_FT      ((size_t)0)            // ft bf16 (B,K,C)
#define OFF_YA      ((size_t)8388608)      // y0/y1 bf16 (M0 x 128)
#define OFF_M2      ((size_t)25165824)     // m2 f32 (M1 x 128)
#define OFF_YF1     ((size_t)27262976)     // yF1 bf16 (M1 x 128)
#define OFF_YF2     ((size_t)28311552)     // yF2 f32 (M1 x 128)
#define OFF_W0T     ((size_t)30408704)     // swizzled bf16 weights
#define OFF_W1T     ((size_t)30425088)
#define OFF_W2T     ((size_t)30433280)
#define OFF_WF1T    ((size_t)30441472)
#define OFF_WF2T    ((size_t)30449664)
#define OFF_STATS   ((size_t)30457856)     // 5 stats x NSLOT x 256 f32
#define OFF_GIDX    ((size_t)30498816)     // 262144 int
#define OFF_NEWXYZ  ((size_t)30760960)

#define ST_STRIDE (NSLOT * 256)

typedef __attribute__((ext_vector_type(8))) short bf16x8;
typedef __attribute__((ext_vector_type(4))) float f32x4;

__device__ __forceinline__ unsigned short f2bf(float x) {
    union { float f; unsigned u; } v; v.f = x;
    unsigned r = v.u + 0x7fffu + ((v.u >> 16) & 1u);  // RNE
    return (unsigned short)(r >> 16);
}
__device__ __forceinline__ float bf2f(unsigned short u) {
    union { unsigned u; float f; } v; v.u = ((unsigned)u) << 16; return v.f;
}

// sum NSLOT slots for channel tid (tid<128): sm=sum, sq=sumsq
__device__ __forceinline__ void read_stats(const float* st, int tid, float& sm, float& sq) {
    sm = 0.f; sq = 0.f;
#pragma unroll
    for (int s = 0; s < NSLOT; ++s) {
        sm += st[s * 256 + tid];
        sq += st[s * 256 + 128 + tid];
    }
}

// ---------------------------------------------------------------- FPS (16 blocks) + fused transpose_feat (1024 blocks)
// + fused weight swizzle (16 blocks). R7 fps body (VGPR 88, 581 us measured).
template <int CTRL>
__device__ __forceinline__ unsigned long long dpp_max_step(unsigned long long key) {
    int lo = (int)(unsigned)key, hi = (int)(key >> 32);
    int slo = __builtin_amdgcn_update_dpp(0, lo, CTRL, 0xf, 0xf, true);
    int shi = __builtin_amdgcn_update_dpp(0, hi, CTRL, 0xf, 0xf, true);
    unsigned long long other = ((unsigned long long)(unsigned)shi << 32) | (unsigned)slo;
    return other > key ? other : key;
}

__global__ __launch_bounds__(256) void fps_fused(const float* __restrict__ xyz, float* __restrict__ new_xyz,
                                                 const float* __restrict__ features, unsigned short* __restrict__ ft,
                                                 const float* __restrict__ w0, const float* __restrict__ w1m,
                                                 const float* __restrict__ w2m, const float* __restrict__ wf1,
                                                 const float* __restrict__ wf2,
                                                 unsigned short* __restrict__ W0T, unsigned short* __restrict__ W1T,
                                                 unsigned short* __restrict__ W2T, unsigned short* __restrict__ WF1T,
                                                 unsigned short* __restrict__ WF2T) {
    __shared__ float4 xyz_s[Kpt];                 // 64 KB (transpose blocks reuse as tile)
    __shared__ unsigned long long red[2][4];
    int bid = blockIdx.x, tid = threadIdx.x;

    if (bid < 16) {
        int b = bid, wid = tid >> 6, lane = tid & 63;
        for (int k = tid; k < Kpt; k += 256) {
            float x = xyz[(size_t)b * Kpt * 3 + k * 3 + 0];
            float y = xyz[(size_t)b * Kpt * 3 + k * 3 + 1];
            float z = xyz[(size_t)b * Kpt * 3 + k * 3 + 2];
            xyz_s[k] = make_float4(x, y, z, 0.f);
        }
        __syncthreads();
        float px[16], py[16], pz[16], mind[16];
#pragma unroll
        for (int j = 0; j < 16; ++j) {
            float4 p = xyz_s[tid + j * 256];
            px[j] = p.x; py[j] = p.y; pz[j] = p.z;
            mind[j] = 1e10f;
        }
        float lx = xyz_s[0].x, ly = xyz_s[0].y, lz = xyz_s[0].z;
        if (tid == 0) {
            new_xyz[(size_t)b * Pnp * 3 + 0] = lx;
            new_xyz[(size_t)b * Pnp * 3 + 1] = ly;
            new_xyz[(size_t)b * Pnp * 3 + 2] = lz;
        }
        for (int it = 1; it < Pnp; ++it) {
            float bestv = -1.0f;
            int bestk = 0;
#pragma unroll
            for (int j = 0; j < 16; ++j) {
                float dx = __fsub_rn(px[j], lx);
                float dy = __fsub_rn(py[j], ly);
                float dz = __fsub_rn(pz[j], lz);
                float d = __fadd_rn(__fadd_rn(__fmul_rn(dx, dx), __fmul_rn(dy, dy)), __fmul_rn(dz, dz));
                float m = fminf(mind[j], d);
                mind[j] = m;
                if (m > bestv) { bestv = m; bestk = tid + j * 256; }
            }
            unsigned long long key = ((unsigned long long)__float_as_uint(bestv) << 32) | (unsigned)(~bestk);
            key = dpp_max_step<0x111>(key);
            key = dpp_max_step<0x112>(key);
            key = dpp_max_step<0x114>(key);
            key = dpp_max_step<0x118>(key);
            key = dpp_max_step<0x142>(key);
            key = dpp_max_step<0x143>(key);
            if (lane == 63) red[it & 1][wid] = key;
            __syncthreads();
            unsigned long long gkey = red[it & 1][0];
#pragma unroll
            for (int w = 1; w < 4; ++w) {
                unsigned long long ok = red[it & 1][w];
                if (ok > gkey) gkey = ok;
            }
            int win = (int)(~(unsigned)gkey);
            float4 c = xyz_s[win];
            lx = c.x; ly = c.y; lz = c.z;
            if (tid == 0) {
                size_t bp = (size_t)b * Pnp + it;
                new_xyz[bp * 3 + 0] = c.x;
                new_xyz[bp * 3 + 1] = c.y;
                new_xyz[bp * 3 + 2] = c.z;
            }
        }
    } else if (bid < 16 + 1024) {
        float* tile = (float*)xyz_s;              // 32x33 f32
        int tx = tid & 31, ty = tid >> 5;         // 32 x 8
        int t0 = (bid - 16) * 16;
        for (int tt = 0; tt < 16; ++tt) {
            int t = t0 + tt;
            int k0 = (t & 127) << 5;
            int c0 = ((t >> 7) & 7) << 5;
            int b2 = t >> 10;
            __syncthreads();
#pragma unroll
            for (int j = 0; j < 4; ++j)
                tile[(ty + j * 8) * 33 + tx] = features[((size_t)b2 * Cft + c0 + ty + j * 8) * Kpt + k0 + tx];
            __syncthreads();
#pragma unroll
            for (int j = 0; j < 4; ++j)
                ft[((size_t)b2 * Kpt + k0 + ty + j * 8) * Cft + c0 + tx] = f2bf(tile[tx * 33 + ty + j * 8]);
        }
    } else {
        int base = (bid - (16 + 1024)) * 6144;
#pragma unroll 1
        for (int i = 0; i < 24; ++i) {
            int e = base + i * 256 + tid;
            const float* src; unsigned short* dst; int eo, stride, off;
            if (e < 32768) { src = w0; dst = W0T; eo = e; stride = 259; off = 3; }
            else {
                int r = e - 32768; int which = r >> 14; eo = r & 16383; stride = 128; off = 0;
                src = (which == 0) ? w1m : (which == 1) ? w2m : (which == 2) ? wf1 : wf2;
                dst = (which == 0) ? W1T : (which == 1) ? W2T : (which == 2) ? WF1T : WF2T;
            }
            int j = eo & 7, np = (eo >> 3) & 15, q = (eo >> 7) & 3, S = (eo >> 9) & 7, c = eo >> 12;
            dst[eo] = f2bf(src[(size_t)(S * 16 + np) * stride + off + c * 32 + q * 8 + j]);
        }
    }
}

// ---------------------------------------------------------------- ball query: no early break -> rounds fully pipelined.
// Result-identical: lanes with have+rank>=16 never write; have only used as min(have,16).
__global__ __launch_bounds__(256) void ballq_kernel(const float* __restrict__ xyz, const float* __restrict__ new_xyz,
                                                    int* __restrict__ gidx) {
    __shared__ float4 xyz_s[Kpt];    // 64 KB, one ds_read_b128 per point
    __shared__ int idxbuf[64][16];
    __shared__ int have_s[64];
    int bx = blockIdx.x;
    int b = bx >> 4, chunk = bx & 15;
    int tid = threadIdx.x, w = tid >> 6, lane = tid & 63;
    for (int k = tid; k < Kpt; k += 256) {
        float x = xyz[(size_t)b * Kpt * 3 + k * 3 + 0];
        float y = xyz[(size_t)b * Kpt * 3 + k * 3 + 1];
        float z = xyz[(size_t)b * Kpt * 3 + k * 3 + 2];
        xyz_s[k] = make_float4(x, y, z, 0.f);
    }
    __syncthreads();
    const float R2 = (float)(0.3 * 0.3);
    unsigned long long lmask = (lane == 63) ? 0x7fffffffffffffffull : ((1ull << lane) - 1ull);
    for (int t = 0; t < 16; ++t) {
        int ql = w * 16 + t;
        size_t bp = (size_t)b * Pnp + chunk * 64 + ql;
        float nx = new_xyz[bp * 3 + 0], ny = new_xyz[bp * 3 + 1], nz = new_xyz[bp * 3 + 2];
        int have = 0;
#pragma unroll 4
        for (int r = 0; r < 64; ++r) {
            int k = r * 64 + lane;
            float4 p = xyz_s[k];
            float dx = __fsub_rn(nx, p.x);
            float dy = __fsub_rn(ny, p.y);
            float dz = __fsub_rn(nz, p.z);
            float d2 = __fadd_rn(__fadd_rn(__fmul_rn(dx, dx), __fmul_rn(dy, dy)), __fmul_rn(dz, dz));
            bool inb = d2 < R2;
            unsigned long long mask = __ballot(inb);
            int rank = __popcll(mask & lmask);
            if (inb && (have + rank) < 16) idxbuf[ql][have + rank] = k;
            have += __popcll(mask);
        }
        if (lane == 0) have_s[ql] = (have > 16) ? 16 : have;
    }
    __syncthreads();
    for (int e = tid; e < 1024; e += 256) {
        int ql = e >> 4, slot = e & 15;
        int h = have_s[ql];
        int v = (h == 0) ? (Kpt - 1) : ((slot < h) ? idxbuf[ql][slot] : idxbuf[ql][0]);
        size_t bp = (size_t)b * Pnp + chunk * 64 + ql;
        gidx[bp * 16 + slot] = v;
    }
}

// ---------------------------------------------------------------- GEMM0: gather + K=256 bf16 MFMA + f32 xyz epilogue,
// out bf16, slotted fused stats. B fragments loaded straight from global (pre-swizzled, L2-hot).
__global__ __launch_bounds__(256) void gemm0_mfma(const unsigned short* __restrict__ ft, const unsigned short* __restrict__ Bsw,
                                                  const float* __restrict__ xyz, const float* __restrict__ new_xyz,
                                                  const int* __restrict__ gidx, const float* __restrict__ w0,
                                                  unsigned short* __restrict__ yout, float* __restrict__ statsOut) {
    __shared__ unsigned short Asw[128 * 256];   // 64 KB
    __shared__ float4 gxyz_s[128];
    __shared__ float4 w03s[128];
    __shared__ int krow_s[128];
    __shared__ float ssum[128], ssq[128];
    int tid = threadIdx.x;
    int wave = tid >> 6, lane = tid & 63, q = lane >> 4, l = lane & 15;
    int wm = wave >> 1, wn = wave & 1;
    size_t r0 = (size_t)blockIdx.x * 128;
    int b = (int)(r0 >> 14);

    if (tid < 128) {
        ssum[tid] = 0.f; ssq[tid] = 0.f;
        size_t r = r0 + tid;
        int kg = gidx[r];
        krow_s[tid] = kg;
        size_t bp = r >> 4;
        float gx = (xyz[((size_t)b * Kpt + kg) * 3 + 0] - new_xyz[bp * 3 + 0]) / 0.3f;
        float gy = (xyz[((size_t)b * Kpt + kg) * 3 + 1] - new_xyz[bp * 3 + 1]) / 0.3f;
        float gz = (xyz[((size_t)b * Kpt + kg) * 3 + 2] - new_xyz[bp * 3 + 2]) / 0.3f;
        gxyz_s[tid] = make_float4(gx, gy, gz, 0.f);
    } else {
        int o = tid - 128;
        w03s[o] = make_float4(w0[(size_t)o * 259 + 0], w0[(size_t)o * 259 + 1], w0[(size_t)o * 259 + 2], 0.f);
    }
    __syncthreads();
#pragma unroll
    for (int i = 0; i < 16; ++i) {
        int idx = i * 4 + wave;
        int G = idx >> 3, c = idx & 7;
        int kg = krow_s[G * 16 + l];
        const unsigned short* src = ft + ((size_t)b * Kpt + kg) * 256 + c * 32 + q * 8;
        *(int4*)&Asw[(size_t)((c * 8 + G) * 64 + lane) * 8] = *(const int4*)src;
    }
    __syncthreads();

    f32x4 acc[4][4];
    f32x4 zz = {0.f, 0.f, 0.f, 0.f};
#pragma unroll
    for (int mi = 0; mi < 4; ++mi)
#pragma unroll
        for (int ni = 0; ni < 4; ++ni) acc[mi][ni] = zz;

    for (int c = 0; c < 8; ++c) {
        bf16x8 af[4], bfr[4];
#pragma unroll
        for (int ni = 0; ni < 4; ++ni)
            bfr[ni] = *(const bf16x8*)&Bsw[(size_t)((c * 8 + wn * 4 + ni) * 64 + lane) * 8];
#pragma unroll
        for (int mi = 0; mi < 4; ++mi)
            af[mi] = *(const bf16x8*)&Asw[(size_t)((c * 8 + wm * 4 + mi) * 64 + lane) * 8];
#pragma unroll
        for (int mi = 0; mi < 4; ++mi)
#pragma unroll
            for (int ni = 0; ni < 4; ++ni)
                acc[mi][ni] = __builtin_amdgcn_mfma_f32_16x16x32_bf16(af[mi], bfr[ni], acc[mi][ni], 0, 0, 0);
    }
    float4 wv[4];
#pragma unroll
    for (int ni = 0; ni < 4; ++ni) wv[ni] = w03s[wn * 64 + ni * 16 + l];
    float psum[4] = {0.f, 0.f, 0.f, 0.f}, psq[4] = {0.f, 0.f, 0.f, 0.f};
#pragma unroll
    for (int mi = 0; mi < 4; ++mi) {
#pragma unroll
        for (int r = 0; r < 4; ++r) {
            int mloc = wm * 64 + mi * 16 + q * 4 + r;
            float4 g = gxyz_s[mloc];
            size_t rowg = r0 + mloc;
#pragma unroll
            for (int ni = 0; ni < 4; ++ni) {
                int colg = wn * 64 + ni * 16 + l;
                float val = acc[mi][ni][r] + g.x * wv[ni].x + g.y * wv[ni].y + g.z * wv[ni].z;
                psum[ni] += val; psq[ni] += val * val;
                yout[rowg * 128 + colg] = f2bf(val);
            }
        }
    }
#pragma unroll
    for (int ni = 0; ni < 4; ++ni) {
        float s = psum[ni], sq = psq[ni];
        s += __shfl_xor(s, 16); sq += __shfl_xor(sq, 16);
        s += __shfl_xor(s, 32); sq += __shfl_xor(sq, 32);
        if (q == 0) {
            int colg = wn * 64 + ni * 16 + l;
            atomicAdd(&ssum[colg], s);
            atomicAdd(&ssq[colg], sq);
        }
    }
    __syncthreads();
    if (tid < 128) {
        float* stSlot = statsOut + (blockIdx.x & (NSLOT - 1)) * 256;
        atomicAdd(&stSlot[tid], ssum[tid]);
        atomicAdd(&stSlot[128 + tid], ssq[tid]);
    }
}

// ---------------------------------------------------------------- generic K=128 bf16 MFMA GEMM: A bf16 or f32 (+opt BN-ReLU),
// opt bias, out bf16 or f32, slotted fused stats. B from global. In-place safe.
__global__ __launch_bounds__(256) void gemm_mfma_bn(const unsigned short* __restrict__ A, const float* __restrict__ Af32,
                                                    const unsigned short* __restrict__ Bsw,
                                                    unsigned short* __restrict__ OutBf, float* __restrict__ OutF,
                                                    const float* __restrict__ statsIn, const float* __restrict__ gamma,
                                                    const float* __restrict__ beta, const float* __restrict__ bias,
                                                    float invN, float* __restrict__ statsOut) {
    __shared__ unsigned short Asw[128 * 128];   // 32 KB
    __shared__ float scs[128], shs[128], ssum[128], ssq[128];
    int tid = threadIdx.x;
    int wave = tid >> 6, lane = tid & 63, q = lane >> 4, l = lane & 15;
    int wm = wave >> 1, wn = wave & 1;
    size_t r0 = (size_t)blockIdx.x * 128;
    bool hasT = (statsIn != nullptr);
    if (tid < 128) {
        ssum[tid] = 0.f; ssq[tid] = 0.f;
        if (hasT) {
            float sm, sq;
            read_stats(statsIn, tid, sm, sq);
            float m = sm * invN;
            float v = sq * invN - m * m;
            float sc = gamma[tid] / sqrtf(v + 1e-5f);
            scs[tid] = sc;
            shs[tid] = beta[tid] - m * sc;
        }
    }
    __syncthreads();
#pragma unroll
    for (int i = 0; i < 8; ++i) {
        int idx = i * 4 + wave;
        int G = idx >> 2, c = idx & 3;
        int cb = c * 32 + q * 8;
        int4 v;
        if (Af32) {
            const float* srcf = Af32 + (r0 + G * 16 + l) * 128 + cb;
            float4 v0 = *(const float4*)srcf;
            float4 v1 = *(const float4*)(srcf + 4);
            float vv[8] = {v0.x, v0.y, v0.z, v0.w, v1.x, v1.y, v1.z, v1.w};
            unsigned short* u = (unsigned short*)&v;
#pragma unroll
            for (int t = 0; t < 8; ++t) {
                float f = vv[t];
                if (hasT) f = fmaxf(0.f, f * scs[cb + t] + shs[cb + t]);
                u[t] = f2bf(f);
            }
        } else {
            const unsigned short* src = A + (r0 + G * 16 + l) * 128 + cb;
            v = *(const int4*)src;
            if (hasT) {
                unsigned short* u = (unsigned short*)&v;
#pragma unroll
                for (int t = 0; t < 8; ++t) {
                    float f = bf2f(u[t]);
                    u[t] = f2bf(fmaxf(0.f, f * scs[cb + t] + shs[cb + t]));
                }
            }
        }
        *(int4*)&Asw[(size_t)((c * 8 + G) * 64 + lane) * 8] = v;
    }
    __syncthreads();

    f32x4 acc[4][4];
    f32x4 zz = {0.f, 0.f, 0.f, 0.f};
#pragma unroll
    for (int mi = 0; mi < 4; ++mi)
#pragma unroll
        for (int ni = 0; ni < 4; ++ni) acc[mi][ni] = zz;

#pragma unroll
    for (int c = 0; c < 4; ++c) {
        bf16x8 af[4], bfr[4];
#pragma unroll
        for (int ni = 0; ni < 4; ++ni)
            bfr[ni] = *(const bf16x8*)&Bsw[(size_t)((c * 8 + wn * 4 + ni) * 64 + lane) * 8];
#pragma unroll
        for (int mi = 0; mi < 4; ++mi)
            af[mi] = *(const bf16x8*)&Asw[(size_t)((c * 8 + wm * 4 + mi) * 64 + lane) * 8];
#pragma unroll
        for (int mi = 0; mi < 4; ++mi)
#pragma unroll
            for (int ni = 0; ni < 4; ++ni)
                acc[mi][ni] = __builtin_amdgcn_mfma_f32_16x16x32_bf16(af[mi], bfr[ni], acc[mi][ni], 0, 0, 0);
    }
    float psum[4] = {0.f, 0.f, 0.f, 0.f}, psq[4] = {0.f, 0.f, 0.f, 0.f};
#pragma unroll
    for (int mi = 0; mi < 4; ++mi) {
#pragma unroll
        for (int r = 0; r < 4; ++r) {
            size_t rowg = r0 + wm * 64 + mi * 16 + q * 4 + r;
#pragma unroll
            for (int ni = 0; ni < 4; ++ni) {
                int colg = wn * 64 + ni * 16 + l;
                float val = acc[mi][ni][r] + (bias ? bias[colg] : 0.f);
                psum[ni] += val; psq[ni] += val * val;
                if (OutBf) OutBf[rowg * 128 + colg] = f2bf(val);
                else OutF[rowg * 128 + colg] = val;
            }
        }
    }
#pragma unroll
    for (int ni = 0; ni < 4; ++ni) {
        float s = psum[ni], sq = psq[ni];
        s += __shfl_xor(s, 16); sq += __shfl_xor(sq, 16);
        s += __shfl_xor(s, 32); sq += __shfl_xor(sq, 32);
        if (q == 0) {
            int colg = wn * 64 + ni * 16 + l;
            atomicAdd(&ssum[colg], s);
            atomicAdd(&ssq[colg], sq);
        }
    }
    __syncthreads();
    if (tid < 128) {
        float* stSlot = statsOut + (blockIdx.x & (NSLOT - 1)) * 256;
        atomicAdd(&stSlot[tid], ssum[tid]);
        atomicAdd(&stSlot[128 + tid], ssq[tid]);
    }
}

// ---------------------------------------------------------------- GEMM2: A bf16 + BN1-ReLU, no y2 write; slotted stats2 +
// per-16-row-group max (BN2 monotone: max commutes with relu∘bn). B from global.
__global__ __launch_bounds__(256) void gemm2_max(const unsigned short* __restrict__ A, const unsigned short* __restrict__ Bsw,
                                                 const float* __restrict__ statsIn, const float* __restrict__ gamma,
                                                 const float* __restrict__ beta, float invN,
                                                 float* __restrict__ m2, float* __restrict__ statsOut) {
    __shared__ unsigned short Asw[128 * 128];
    __shared__ float scs[128], shs[128], ssum[128], ssq[128];
    __shared__ float smax[8][128];
    int tid = threadIdx.x;
    int wave = tid >> 6, lane = tid & 63, q = lane >> 4, l = lane & 15;
    int wm = wave >> 1, wn = wave & 1;
    size_t r0 = (size_t)blockIdx.x * 128;
    if (tid < 128) {
        ssum[tid] = 0.f; ssq[tid] = 0.f;
        float sm, sq;
        read_stats(statsIn, tid, sm, sq);
        float m = sm * invN;
        float v = sq * invN - m * m;
        float sc = gamma[tid] / sqrtf(v + 1e-5f);
        scs[tid] = sc;
        shs[tid] = beta[tid] - m * sc;
    }
    __syncthreads();
#pragma unroll
    for (int i = 0; i < 8; ++i) {
        int idx = i * 4 + wave;
        int G = idx >> 2, c = idx & 3;
        const unsigned short* src = A + (r0 + G * 16 + l) * 128 + c * 32 + q * 8;
        int4 v = *(const int4*)src;
        unsigned short* u = (unsigned short*)&v;
        int cb = c * 32 + q * 8;
#pragma unroll
        for (int t = 0; t < 8; ++t) {
            float f = bf2f(u[t]);
            u[t] = f2bf(fmaxf(0.f, f * scs[cb + t] + shs[cb + t]));
        }
        *(int4*)&Asw[(size_t)((c * 8 + G) * 64 + lane) * 8] = v;
    }
    __syncthreads();

    f32x4 acc[4][4];
    f32x4 zz = {0.f, 0.f, 0.f, 0.f};
#pragma unroll
    for (int mi = 0; mi < 4; ++mi)
#pragma unroll
        for (int ni = 0; ni < 4; ++ni) acc[mi][ni] = zz;

#pragma unroll
    for (int c = 0; c < 4; ++c) {
        bf16x8 af[4], bfr[4];
#pragma unroll
        for (int ni = 0; ni < 4; ++ni)
            bfr[ni] = *(const bf16x8*)&Bsw[(size_t)((c * 8 + wn * 4 + ni) * 64 + lane) * 8];
#pragma unroll
        for (int mi = 0; mi < 4; ++mi)
            af[mi] = *(const bf16x8*)&Asw[(size_t)((c * 8 + wm * 4 + mi) * 64 + lane) * 8];
#pragma unroll
        for (int mi = 0; mi < 4; ++mi)
#pragma unroll
            for (int ni = 0; ni < 4; ++ni)
                acc[mi][ni] = __builtin_amdgcn_mfma_f32_16x16x32_bf16(af[mi], bfr[ni], acc[mi][ni], 0, 0, 0);
    }
    float psum[4] = {0.f, 0.f, 0.f, 0.f}, psq[4] = {0.f, 0.f, 0.f, 0.f};
#pragma unroll
    for (int mi = 0; mi < 4; ++mi) {
#pragma unroll
        for (int ni = 0; ni < 4; ++ni) {
            float gm = -1e30f;
#pragma unroll
            for (int r = 0; r < 4; ++r) {
                float val = acc[mi][ni][r];
                psum[ni] += val; psq[ni] += val * val;
                gm = fmaxf(gm, val);
            }
            gm = fmaxf(gm, __shfl_xor(gm, 16));
            gm = fmaxf(gm, __shfl_xor(gm, 32));
            if (q == 0) smax[wm * 4 + mi][wn * 64 + ni * 16 + l] = gm;
        }
    }
#pragma unroll
    for (int ni = 0; ni < 4; ++ni) {
        float s = psum[ni], sq = psq[ni];
        s += __shfl_xor(s, 16); sq += __shfl_xor(sq, 16);
        s += __shfl_xor(s, 32); sq += __shfl_xor(sq, 32);
        if (q == 0) {
            int colg = wn * 64 + ni * 16 + l;
            atomicAdd(&ssum[colg], s);
            atomicAdd(&ssq[colg], sq);
        }
    }
    __syncthreads();
#pragma unroll
    for (int i = 0; i < 4; ++i) {
        int e = i * 256 + tid;
        int g = e >> 7, cc = e & 127;
        m2[((size_t)blockIdx.x * 8 + g) * 128 + cc] = smax[g][cc];
    }
    if (tid < 128) {
        float* stSlot = statsOut + (blockIdx.x & (NSLOT - 1)) * 256;
        atomicAdd(&stSlot[tid], ssum[tid]);
        atomicAdd(&stSlot[128 + tid], ssq[tid]);
    }
}

// ---------------------------------------------------------------- final: n2=BN-ReLU(yf), net=n2@w3^T+b3, out assembly
__global__ __launch_bounds__(256) void final_k(const float* __restrict__ yf, const float* __restrict__ st,
                                               const float* __restrict__ gamma, const float* __restrict__ beta,
                                               const float* __restrict__ w3, const float* __restrict__ b3,
                                               const float* __restrict__ new_xyz, float* __restrict__ out) {
    __shared__ float n2s[8][128];
    __shared__ float w3s[22 * 132];
    __shared__ float scf[128], shf[128];
    int tid = threadIdx.x;
    size_t r0 = (size_t)blockIdx.x * 8;
    if (tid < 128) {
        const float invN = 1.f / (float)M1;
        float sm, sq;
        read_stats(st, tid, sm, sq);
        float m = sm * invN;
        float v = sq * invN - m * m;
        float sc = gamma[tid] / sqrtf(v + 1e-5f);
        scf[tid] = sc;
        shf[tid] = beta[tid] - m * sc;
    }
    __syncthreads();
#pragma unroll
    for (int i = 0; i < 4; ++i) {
        int e = tid + i * 256;
        int rl = e >> 7, c = e & 127;
        float raw = yf[(r0 + rl) * 128 + c];
        n2s[rl][c] = fmaxf(0.f, raw * scf[c] + shf[c]);
    }
#pragma unroll
    for (int i = 0; i < 11; ++i) {
        int e = tid + i * 256;
        int o = e >> 7, c = e & 127;
        w3s[o * 132 + c] = w3[e];
    }
    __syncthreads();
    int rl = tid >> 5, o = tid & 31;
    if (o < OUTCH) {
        float dot = 0.f;
#pragma unroll 4
        for (int c = 0; c < 128; ++c) dot += n2s[rl][c] * w3s[o * 132 + c];
        float v = dot + b3[o];
        if (o < 3) v += new_xyz[(r0 + rl) * 3 + o];
        out[(r0 + rl) * OUTCH + o] = v;
    }
}

extern "C" void kernel_launch(void* const* d_in, const int* in_sizes, int n_in,
                              void* d_out, int out_size, void* d_ws, size_t ws_size,
                              hipStream_t stream) {
    (void)in_sizes; (void)n_in; (void)out_size; (void)ws_size;
    const float* xyz = (const float*)d_in[0];
    const float* features = (const float*)d_in[1];
    const float* w0 = (const float*)d_in[2];
    const float* g0 = (const float*)d_in[3];
    const float* be0 = (const float*)d_in[4];
    const float* w1m = (const float*)d_in[5];
    const float* g1m = (const float*)d_in[6];
    const float* be1m = (const float*)d_in[7];
    const float* w2m = (const float*)d_in[8];
    const float* g2m = (const float*)d_in[9];
    const float* be2m = (const float*)d_in[10];
    const float* wf1 = (const float*)d_in[11];
    const float* bf1 = (const float*)d_in[12];
    const float* gf1 = (const float*)d_in[13];
    const float* bef1 = (const float*)d_in[14];
    const float* wf2 = (const float*)d_in[15];
    const float* bf2 = (const float*)d_in[16];
    const float* gf2 = (const float*)d_in[17];
    const float* bef2 = (const float*)d_in[18];
    const float* w3 = (const float*)d_in[19];
    const float* b3 = (const float*)d_in[20];
    float* ws = (float*)d_ws;
    unsigned short* ft = (unsigned short*)(ws + OFF_FT);
    unsigned short* yA = (unsigned short*)(ws + OFF_YA);
    float* m2 = ws + OFF_M2;
    unsigned short* yF1 = (unsigned short*)(ws + OFF_YF1);
    float* yF2 = ws + OFF_YF2;
    unsigned short* W0T = (unsigned short*)(ws + OFF_W0T);
    unsigned short* W1T = (unsigned short*)(ws + OFF_W1T);
    unsigned short* W2T = (unsigned short*)(ws + OFF_W2T);
    unsigned short* WF1T = (unsigned short*)(ws + OFF_WF1T);
    unsigned short* WF2T = (unsigned short*)(ws + OFF_WF2T);
    float* st = ws + OFF_STATS;          // 5 x NSLOT x 256
    int* gidx = (int*)(ws + OFF_GIDX);
    float* nxyz = ws + OFF_NEWXYZ;

    hipMemsetAsync((void*)st, 0, 5 * ST_STRIDE * sizeof(float), stream);

    fps_fused<<<16 + 1024 + 16, 256, 0, stream>>>(xyz, nxyz, features, ft,
                                                  w0, w1m, w2m, wf1, wf2,
                                                  W0T, W1T, W2T, WF1T, WF2T);
    ballq_kernel<<<256, 256, 0, stream>>>(xyz, nxyz, gidx);

    // st0 = stats(y0), st1 = stats(y1), st2 = stats(y2), st3 = stats(yF1), st4 = stats(yF2)
    gemm0_mfma<<<M0 / 128, 256, 0, stream>>>(ft, W0T, xyz, nxyz, gidx, w0, yA, st);
    gemm_mfma_bn<<<M0 / 128, 256, 0, stream>>>(yA, nullptr, W1T, yA, nullptr,
                                               st, g0, be0, nullptr, 1.f / (float)M0, st + ST_STRIDE);
    gemm2_max<<<M0 / 128, 256, 0, stream>>>(yA, W2T, st + ST_STRIDE, g1m, be1m, 1.f / (float)M0,
                                            m2, st + 2 * ST_STRIDE);
    // gemmF1: A = BN2-ReLU(m2) [f32 path], out yF1 bf16 + bias bf1, stats -> st3
    gemm_mfma_bn<<<M1 / 128, 256, 0, stream>>>(nullptr, m2, WF1T, yF1, nullptr,
                                               st + 2 * ST_STRIDE, g2m, be2m, bf1, 1.f / (float)M0, st + 3 * ST_STRIDE);
    // gemmF2: A = BN3-ReLU(yF1) [bf16], out yF2 f32 + bias bf2, stats -> st4
    gemm_mfma_bn<<<M1 / 128, 256, 0, stream>>>(yF1, nullptr, WF2T, nullptr, yF2,
                                               st + 3 * ST_STRIDE, gf1, bef1, bf2, 1.f / (float)M1, st + 4 * ST_STRIDE);
    final_k<<<M1 / 8, 256, 0, stream>>>(yF2, st + 4 * ST_STRIDE, gf2, bef2, w3, b3, nxyz, (float*)d_out);
}